// Round 7
// baseline (49.361 us; speedup 1.0000x reference)
//
#include <hip/hip_runtime.h>

// ChebychevTransform: x[8,256,256,8] f32 -> out[8,256,256,128] f32
// out[b,h,w, c*16+p*4+k] = sum_{j,i} T[p][j]*T[k][i]*xpad[b,h+i-1,w+j-1,c]
//
// R2: nontemporal 16B lane-strided stores -> partial-line bursts, 728MB. 337us.
// R3: cached stores, L2 merges -> 268MB, but 4x store transactions. 88.9us.
// R4: LDS-staged store transpose (full-line wave stores). 55.6us.
// R5: interior fast-path + butterfly DCT + nt full-line stores. 50.5us.
// R6: single-wave blocks, no barrier. 48.1us.
// R7: 256-thread blocks of 4 INDEPENDENT waves (private LDS quarters, still
//     zero barriers) — restores WG-dispatch density (8 blocks = 32 waves/CU)
//     in case the 16-WG/CU cap was limiting R6 to 16 waves/CU.

#define H_DIM 256
#define W_DIM 256
#define C_DIM 8
#define B_DIM 8

typedef float f32x4 __attribute__((ext_vector_type(4)));

// 4-point DCT-I butterfly: y = T*v with
// T = [[1/6,1/3,1/3,1/6],[1/3,1/3,-1/3,-1/3],[1/3,-1/3,-1/3,1/3],[1/3,-2/3,2/3,-1/3]]
__device__ __forceinline__ void cheb4(const float v0, const float v1,
                                      const float v2, const float v3,
                                      float& y0, float& y1, float& y2, float& y3) {
    const float a = v0 + v3;
    const float bb = v1 + v2;
    const float d = v0 - v3;
    const float e = v1 - v2;
    y0 = a * (1.f / 6.f) + bb * (1.f / 3.f);
    y1 = (d + e) * (1.f / 3.f);
    y2 = (a - bb) * (1.f / 3.f);
    y3 = d * (1.f / 3.f) - e * (2.f / 3.f);
}

__global__ __launch_bounds__(256) void cheb_kernel(const float* __restrict__ x,
                                                   float* __restrict__ out) {
    __shared__ f32x4 lds[1024];           // 16 KB; wave wv owns lds[wv*256..+256)

    const int t = threadIdx.x;            // 0..255
    const int lane = t & 63;
    const int wv = t >> 6;
    const int bid = blockIdx.x;
    // tid = bid*256+t = ((b*256 + h)*256 + w)*8 + c
    const int c = t & 7;
    const int w = ((bid & 7) << 5) | (t >> 3);
    const int h = (bid >> 3) & 255;
    const int b = bid >> 11;

    // Load 4x4 patch: v[j][i] = xpad[b, h+i-1, w+j-1, c] (zero outside).
    float v[4][4];
    const bool interior = (h >= 1) & (h <= H_DIM - 3) & (w >= 1) & (w <= W_DIM - 3);
    if (interior) {
        const float* p0 = x + (((((size_t)b * H_DIM + (h - 1)) * W_DIM) + (w - 1)) * C_DIM) + c;
#pragma unroll
        for (int i = 0; i < 4; ++i) {
#pragma unroll
            for (int j = 0; j < 4; ++j) {
                v[j][i] = p0[i * (W_DIM * C_DIM) + j * C_DIM];
            }
        }
    } else {
#pragma unroll
        for (int i = 0; i < 4; ++i) {
            const int hh = h + i - 1;
            const bool hok = (unsigned)hh < (unsigned)H_DIM;
            const int hc = min(max(hh, 0), H_DIM - 1);
#pragma unroll
            for (int j = 0; j < 4; ++j) {
                const int ww = w + j - 1;
                const bool ok = hok && ((unsigned)ww < (unsigned)W_DIM);
                const int wc = min(max(ww, 0), W_DIM - 1);
                const size_t idx = ((((size_t)b * H_DIM + hc) * W_DIM + wc) * C_DIM) + c;
                const float val = x[idx];   // address always in-bounds (clamped)
                v[j][i] = ok ? val : 0.0f;
            }
        }
    }

    // Row transform (over i): tmp[j][k] = sum_i T[k][i]*v[j][i]
    float tmp[4][4];
#pragma unroll
    for (int j = 0; j < 4; ++j)
        cheb4(v[j][0], v[j][1], v[j][2], v[j][3],
              tmp[j][0], tmp[j][1], tmp[j][2], tmp[j][3]);

    // Col transform (over j): o[p][k] = sum_j T[p][j]*tmp[j][k]
    float o[4][4];
#pragma unroll
    for (int k = 0; k < 4; ++k)
        cheb4(tmp[0][k], tmp[1][k], tmp[2][k], tmp[3][k],
              o[0][k], o[1][k], o[2][k], o[3][k]);

    // Stash in this wave's private LDS quarter, XOR-swizzled (bank-uniform).
    // Same-wave RAW only -> no __syncthreads; lgkmcnt orders it.
    f32x4* wlds = lds + wv * 256;
#pragma unroll
    for (int p = 0; p < 4; ++p) {
        f32x4 r;
#pragma unroll
        for (int k = 0; k < 4; ++k) r[k] = o[p][k];
        wlds[p * 64 + (lane ^ p)] = r;
    }

    // Coalesced store: wave wv owns out f4 range [bid*1024 + wv*256, +256).
    // Iteration s, lane emits chunk f4 q = s*64+lane (contiguous 1KB/wave
    // store, full 64B lines -> nontemporal safe).
    f32x4* o4 = reinterpret_cast<f32x4*>(out) + (size_t)bid * 1024 + wv * 256;
#pragma unroll
    for (int s = 0; s < 4; ++s) {
        const int q = s * 64 + lane;
        const int p = q & 3;            // == lane & 3
        const int tp = q >> 2;
        f32x4 r = wlds[p * 64 + (tp ^ p)];
        __builtin_nontemporal_store(r, &o4[q]);
    }
}

extern "C" void kernel_launch(void* const* d_in, const int* in_sizes, int n_in,
                              void* d_out, int out_size, void* d_ws, size_t ws_size,
                              hipStream_t stream) {
    const float* x = (const float*)d_in[0];
    float* out = (float*)d_out;
    const int total_threads = B_DIM * H_DIM * W_DIM * C_DIM;  // 4,194,304
    const int block = 256;
    const int grid = total_threads / block;                   // 16384
    cheb_kernel<<<grid, block, 0, stream>>>(x, out);
}